// Round 4
// baseline (761.783 us; speedup 1.0000x reference)
//
#include <hip/hip_runtime.h>
#include <hip/hip_bf16.h>

typedef unsigned short u16;
typedef __attribute__((ext_vector_type(8))) short bf16x8;
typedef __attribute__((ext_vector_type(4))) float f32x4;

#define NDIM 128
#define EDIM 32

__device__ __forceinline__ float bf2f(u16 u) {
    union { unsigned int i; float f; } v; v.i = ((unsigned int)u) << 16; return v.f;
}
__device__ __forceinline__ u16 f2bf(float f) {
    __hip_bfloat16 h = __float2bfloat16(f);
    return *reinterpret_cast<u16*>(&h);
}

template<bool BF>
__device__ __forceinline__ float ld1(const void* p, long i) {
    if (BF) return bf2f(((const u16*)p)[i]);
    return ((const float*)p)[i];
}
template<bool BF>
__device__ __forceinline__ float4 ld4(const void* p, long i) {
    if (BF) {
        ushort4 v = *(const ushort4*)((const u16*)p + i);
        return make_float4(bf2f(v.x), bf2f(v.y), bf2f(v.z), bf2f(v.w));
    }
    return *(const float4*)((const float*)p + i);
}

// ---------------------------------------------------------------------------
// K0: dtype detector (flag: 1 = bf16, 0 = fp32)
// ---------------------------------------------------------------------------
__global__ void detect_kernel(const void* __restrict__ x, int* __restrict__ flag) {
    __shared__ int cnt;
    if (threadIdx.x == 0) cnt = 0;
    __syncthreads();
    const u16* p = (const u16*)x;
    int crazy = 0;
    for (int i = threadIdx.x; i < 512; i += 64) {
        u16 v = p[2 * i];
        int e = (v >> 7) & 0xFF;
        if (e != 0 && (e < 100 || e > 150)) crazy++;
    }
    atomicAdd(&cnt, crazy);
    __syncthreads();
    if (threadIdx.x == 0) *flag = (cnt > 128) ? 0 : 1;
}

// ---------------------------------------------------------------------------
// CSR build
// ---------------------------------------------------------------------------
__global__ __launch_bounds__(256) void hist_kernel(
    const int* __restrict__ ei, int* __restrict__ cnt, int E) {
    int e = blockIdx.x * 256 + threadIdx.x;
    if (e < E) atomicAdd(&cnt[ei[E + e]], 1);
}

__global__ __launch_bounds__(1024) void scan_kernel(
    const int* __restrict__ cnt, int* __restrict__ row_ptr, int N) {
    __shared__ int part[1024];
    const int t = threadIdx.x;
    const int chunk = (N + 1023) / 1024;
    const int lo = t * chunk;
    const int hi = min(lo + chunk, N);
    int s = 0;
    for (int i = lo; i < hi; ++i) s += cnt[i];
    part[t] = s;
    __syncthreads();
    for (int off = 1; off < 1024; off <<= 1) {
        int v = (t >= off) ? part[t - off] : 0;
        __syncthreads();
        part[t] += v;
        __syncthreads();
    }
    int run = (t == 0) ? 0 : part[t - 1];
    for (int i = lo; i < hi; ++i) { row_ptr[i] = run; run += cnt[i]; }
    if (t == 1023) row_ptr[N] = run;
}

__global__ __launch_bounds__(256) void scatter2_kernel(
    const int* __restrict__ ei, const int* __restrict__ row_ptr,
    int* __restrict__ cur, int* __restrict__ eidx,
    int* __restrict__ src_sorted, int* __restrict__ inv_idx, int E) {
    int e = blockIdx.x * 256 + threadIdx.x;
    if (e < E) {
        int dst = ei[E + e];
        int slot = row_ptr[dst] + atomicAdd(&cur[dst], 1);
        eidx[slot] = e;
        src_sorted[slot] = ei[e];
        inv_idx[e] = slot;
    }
}

// ---------------------------------------------------------------------------
// Pass A: EF[slot] = relu(edge_attr[e] @ We + be), bf16 MFMA, K=32 in one shot.
// Operands swapped: D = We^T @ attr^T, so lane's C-frag = 4 consecutive dims
// of one edge -> ushort4 store. Stores land at CSR slot (inv_idx) so Pass B
// reads sequentially. bf16-only (flag-guarded).
// ---------------------------------------------------------------------------
__global__ __launch_bounds__(256) void ef_kernel(
    const u16* __restrict__ edge_attr, const u16* __restrict__ We,
    const u16* __restrict__ be, const int* __restrict__ inv_idx,
    u16* __restrict__ EF, int E, const int* __restrict__ flag) {
    if (*flag != 1) return;
    const int lane = threadIdx.x & 63;
    const int wave = blockIdx.x * 4 + (threadIdx.x >> 6);
    const int e0 = wave * 64;
    if (e0 >= E) return;
    const int quad = lane >> 4, l16 = lane & 15;

    // A-frags: A[m=l16][k=quad*8+j] = We[k][m0*16+l16], 8 m-tiles (128 dims)
    bf16x8 afrag[8];
#pragma unroll
    for (int m0 = 0; m0 < 8; ++m0)
#pragma unroll
        for (int j = 0; j < 8; ++j)
            afrag[m0][j] = (short)We[(quad * 8 + j) * NDIM + m0 * 16 + l16];

    // bias for this lane's dims: dim = m0*16 + quad*4 + r
    float4 bias[8];
#pragma unroll
    for (int m0 = 0; m0 < 8; ++m0) {
        ushort4 bv = *(const ushort4*)(be + m0 * 16 + quad * 4);
        bias[m0] = make_float4(bf2f(bv.x), bf2f(bv.y), bf2f(bv.z), bf2f(bv.w));
    }

#pragma unroll
    for (int n0 = 0; n0 < 4; ++n0) {
        int edge = e0 + n0 * 16 + l16;
        int ec = min(edge, E - 1);
        // B[k=quad*8+j][n=l16] = attr[edge][k] : contiguous 16B, wave covers 1KB
        bf16x8 bfrag = *(const bf16x8*)(edge_attr + (long)ec * EDIM + quad * 8);
        int slot = inv_idx[ec];
        f32x4 acc[8];
#pragma unroll
        for (int m0 = 0; m0 < 8; ++m0) {
            f32x4 z = {0.0f, 0.0f, 0.0f, 0.0f};
            acc[m0] = __builtin_amdgcn_mfma_f32_16x16x32_bf16(afrag[m0], bfrag, z, 0, 0, 0);
        }
        if (edge < E) {
#pragma unroll
            for (int m0 = 0; m0 < 8; ++m0) {
                ushort4 o;
                o.x = f2bf(fmaxf(acc[m0][0] + bias[m0].x, 0.0f));
                o.y = f2bf(fmaxf(acc[m0][1] + bias[m0].y, 0.0f));
                o.z = f2bf(fmaxf(acc[m0][2] + bias[m0].z, 0.0f));
                o.w = f2bf(fmaxf(acc[m0][3] + bias[m0].w, 0.0f));
                *(ushort4*)(EF + (long)slot * NDIM + m0 * 16 + quad * 4) = o;
            }
        }
    }
}

// ---------------------------------------------------------------------------
// Pass B: agg[n] = sum_slots ( EF[slot] + x[src_sorted[slot]] ).
// One wave per node; lane owns dims {2*lane, 2*lane+1}; EF reads streaming.
// bf16-only (flag-guarded).
// ---------------------------------------------------------------------------
__global__ __launch_bounds__(256) void aggB_kernel(
    const int* __restrict__ row_ptr, const int* __restrict__ src_sorted,
    const u16* __restrict__ EF, const u16* __restrict__ x,
    float* __restrict__ agg, int N, const int* __restrict__ flag) {
    if (*flag != 1) return;
    const int lane = threadIdx.x & 63;
    const int n = blockIdx.x * 4 + (threadIdx.x >> 6);
    if (n >= N) return;
    const int p0 = row_ptr[n], p1 = row_ptr[n + 1];
    const int d = 2 * lane;
    float a0 = 0.0f, a1 = 0.0f;
    int s_next = (p0 < p1) ? src_sorted[p0] : 0;
    for (int p = p0; p < p1; ++p) {
        int s = s_next;
        if (p + 1 < p1) s_next = src_sorted[p + 1];
        ushort2 ev = *(const ushort2*)(EF + (long)p * NDIM + d);
        ushort2 xv = *(const ushort2*)(x + (long)s * NDIM + d);
        a0 += bf2f(ev.x) + bf2f(xv.x);
        a1 += bf2f(ev.y) + bf2f(xv.y);
    }
    *(float2*)(agg + (long)n * NDIM + d) = make_float2(a0, a1);
}

// ---------------------------------------------------------------------------
// Fallback CSR aggregation (R3 path) — used when ws too small, or fp32 data.
// ---------------------------------------------------------------------------
template<bool BF>
__global__ __launch_bounds__(256) void agg_kernel(
    const int* __restrict__ row_ptr, const int* __restrict__ eidx,
    const int* __restrict__ ei, const void* __restrict__ edge_attr,
    const void* __restrict__ x, const void* __restrict__ We,
    const void* __restrict__ be, float* __restrict__ agg, int N,
    const int* __restrict__ flag) {
    if ((*flag != 0) != BF) return;
    __shared__ float WeLds[EDIM * NDIM];
    __shared__ float beLds[NDIM];
    for (int i = threadIdx.x; i < EDIM * NDIM; i += 256) WeLds[i] = ld1<BF>(We, i);
    if (threadIdx.x < NDIM) beLds[threadIdx.x] = ld1<BF>(be, threadIdx.x);
    __syncthreads();

    const int lane = threadIdx.x & 63;
    const int gwave = blockIdx.x * 4 + (threadIdx.x >> 6);
    const int nwaves = gridDim.x * 4;

    for (int n = gwave; n < N; n += nwaves) {
        const int p0 = row_ptr[n], p1 = row_ptr[n + 1];
        float acc0 = 0.0f, acc1 = 0.0f;
        int src = 0; float av = 0.0f;
        if (p0 < p1) {
            int eid = eidx[p0];
            src = ei[eid];
            av = (lane < EDIM) ? ld1<BF>(edge_attr, (long)eid * EDIM + lane) : 0.0f;
        }
        for (int p = p0; p < p1; ++p) {
            const int csrc = src;
            const float cav = av;
            float xv0 = ld1<BF>(x, (long)csrc * NDIM + lane);
            float xv1 = ld1<BF>(x, (long)csrc * NDIM + 64 + lane);
            if (p + 1 < p1) {
                int eid = eidx[p + 1];
                src = ei[eid];
                av = (lane < EDIM) ? ld1<BF>(edge_attr, (long)eid * EDIM + lane) : 0.0f;
            }
            float e0 = 0.0f, e1 = 0.0f;
#pragma unroll
            for (int k = 0; k < EDIM; ++k) {
                float ak = __shfl(cav, k);
                e0 += ak * WeLds[k * NDIM + lane];
                e1 += ak * WeLds[k * NDIM + 64 + lane];
            }
            acc0 += fmaxf(e0 + beLds[lane], 0.0f) + xv0;
            acc1 += fmaxf(e1 + beLds[64 + lane], 0.0f) + xv1;
        }
        agg[(long)n * NDIM + lane] = acc0;
        agg[(long)n * NDIM + 64 + lane] = acc1;
    }
}

// ---------------------------------------------------------------------------
// K2: h0 = (1+eps)*x + agg ; h1 = h0 @ W1 + b1 ; accumulate col sum/sumsq
// ---------------------------------------------------------------------------
template<bool BF>
__global__ __launch_bounds__(256) void gemm1_kernel(
    const void* __restrict__ x, const float* __restrict__ agg,
    const void* __restrict__ eps_p, const void* __restrict__ W,
    const void* __restrict__ b, float* __restrict__ hout,
    float* __restrict__ stats, int M, const int* __restrict__ flag) {
    if ((*flag != 0) != BF) return;
    __shared__ float hT[64 * 129];
    __shared__ float redS[8][NDIM];
    __shared__ float redQ[8][NDIM];

    const int tid = threadIdx.x;
    const int row0 = blockIdx.x * 64;
    const float onepeps = 1.0f + ld1<BF>(eps_p, 0);

#pragma unroll
    for (int i = 0; i < 8; ++i) {
        int idx = (tid + i * 256) * 4;
        int r = idx >> 7, c = idx & 127;
        int row = row0 + r;
        float v0 = 0.f, v1 = 0.f, v2 = 0.f, v3 = 0.f;
        if (row < M) {
            const float4 ag = *(const float4*)(agg + (long)row * NDIM + c);
            const float4 xv = ld4<BF>(x, (long)row * NDIM + c);
            v0 = onepeps * xv.x + ag.x;
            v1 = onepeps * xv.y + ag.y;
            v2 = onepeps * xv.z + ag.z;
            v3 = onepeps * xv.w + ag.w;
        }
        hT[r * 129 + c + 0] = v0;
        hT[r * 129 + c + 1] = v1;
        hT[r * 129 + c + 2] = v2;
        hT[r * 129 + c + 3] = v3;
    }
    __syncthreads();

    const int tx = tid & 31, ty = tid >> 5;
    const int c0 = tx * 4;
    float acc[8][4];
#pragma unroll
    for (int j = 0; j < 4; ++j) {
        float bj = ld1<BF>(b, c0 + j);
#pragma unroll
        for (int r = 0; r < 8; ++r) acc[r][j] = bj;
    }

    for (int k = 0; k < NDIM; ++k) {
        float4 wv = ld4<BF>(W, (long)k * NDIM + c0);
#pragma unroll
        for (int r = 0; r < 8; ++r) {
            float a = hT[(ty * 8 + r) * 129 + k];
            acc[r][0] += a * wv.x;
            acc[r][1] += a * wv.y;
            acc[r][2] += a * wv.z;
            acc[r][3] += a * wv.w;
        }
    }

    float s0 = 0.f, s1 = 0.f, s2 = 0.f, s3 = 0.f;
    float q0 = 0.f, q1 = 0.f, q2 = 0.f, q3 = 0.f;
#pragma unroll
    for (int r = 0; r < 8; ++r) {
        int row = row0 + ty * 8 + r;
        if (row < M) {
            *(float4*)(hout + (long)row * NDIM + c0) =
                make_float4(acc[r][0], acc[r][1], acc[r][2], acc[r][3]);
            s0 += acc[r][0]; q0 += acc[r][0] * acc[r][0];
            s1 += acc[r][1]; q1 += acc[r][1] * acc[r][1];
            s2 += acc[r][2]; q2 += acc[r][2] * acc[r][2];
            s3 += acc[r][3]; q3 += acc[r][3] * acc[r][3];
        }
    }
    redS[ty][c0] = s0; redS[ty][c0 + 1] = s1; redS[ty][c0 + 2] = s2; redS[ty][c0 + 3] = s3;
    redQ[ty][c0] = q0; redQ[ty][c0 + 1] = q1; redQ[ty][c0 + 2] = q2; redQ[ty][c0 + 3] = q3;
    __syncthreads();
    if (tid < NDIM) {
        float t = 0.f;
#pragma unroll
        for (int w = 0; w < 8; ++w) t += redS[w][tid];
        atomicAdd(&stats[tid], t);
    } else {
        int c = tid - NDIM;
        float t = 0.f;
#pragma unroll
        for (int w = 0; w < 8; ++w) t += redQ[w][c];
        atomicAdd(&stats[NDIM + c], t);
    }
}

// ---------------------------------------------------------------------------
// K3: a = relu(BN1(h1)) ; h2 = a @ W2 + b2 ; accumulate col sum/sumsq
// ---------------------------------------------------------------------------
template<bool BF>
__global__ __launch_bounds__(256) void gemm2_kernel(
    const float* __restrict__ h1, const float* __restrict__ statsIn,
    const void* __restrict__ g, const void* __restrict__ beta,
    const void* __restrict__ W, const void* __restrict__ b,
    float* __restrict__ hout, float* __restrict__ stats, int M,
    const int* __restrict__ flag) {
    if ((*flag != 0) != BF) return;
    __shared__ float hT[64 * 129];
    __shared__ float redS[8][NDIM];
    __shared__ float redQ[8][NDIM];
    __shared__ float scaleL[NDIM];
    __shared__ float shiftL[NDIM];

    const int tid = threadIdx.x;
    const int row0 = blockIdx.x * 64;

    if (tid < NDIM) {
        float s = statsIn[tid], q = statsIn[NDIM + tid];
        float invM = 1.0f / (float)M;
        float mean = s * invM;
        float var = fmaxf(q * invM - mean * mean, 0.0f) + 1e-5f;
        float sc = ld1<BF>(g, tid) * rsqrtf(var);
        scaleL[tid] = sc;
        shiftL[tid] = ld1<BF>(beta, tid) - mean * sc;
    }
    __syncthreads();

#pragma unroll
    for (int i = 0; i < 8; ++i) {
        int idx = (tid + i * 256) * 4;
        int r = idx >> 7, c = idx & 127;
        int row = row0 + r;
        float v0 = 0.f, v1 = 0.f, v2 = 0.f, v3 = 0.f;
        if (row < M) {
            const float4 hv = *(const float4*)(h1 + (long)row * NDIM + c);
            v0 = fmaxf(hv.x * scaleL[c + 0] + shiftL[c + 0], 0.0f);
            v1 = fmaxf(hv.y * scaleL[c + 1] + shiftL[c + 1], 0.0f);
            v2 = fmaxf(hv.z * scaleL[c + 2] + shiftL[c + 2], 0.0f);
            v3 = fmaxf(hv.w * scaleL[c + 3] + shiftL[c + 3], 0.0f);
        }
        hT[r * 129 + c + 0] = v0;
        hT[r * 129 + c + 1] = v1;
        hT[r * 129 + c + 2] = v2;
        hT[r * 129 + c + 3] = v3;
    }
    __syncthreads();

    const int tx = tid & 31, ty = tid >> 5;
    const int c0 = tx * 4;
    float acc[8][4];
#pragma unroll
    for (int j = 0; j < 4; ++j) {
        float bj = ld1<BF>(b, c0 + j);
#pragma unroll
        for (int r = 0; r < 8; ++r) acc[r][j] = bj;
    }

    for (int k = 0; k < NDIM; ++k) {
        float4 wv = ld4<BF>(W, (long)k * NDIM + c0);
#pragma unroll
        for (int r = 0; r < 8; ++r) {
            float a = hT[(ty * 8 + r) * 129 + k];
            acc[r][0] += a * wv.x;
            acc[r][1] += a * wv.y;
            acc[r][2] += a * wv.z;
            acc[r][3] += a * wv.w;
        }
    }

    float s0 = 0.f, s1 = 0.f, s2 = 0.f, s3 = 0.f;
    float q0 = 0.f, q1 = 0.f, q2 = 0.f, q3 = 0.f;
#pragma unroll
    for (int r = 0; r < 8; ++r) {
        int row = row0 + ty * 8 + r;
        if (row < M) {
            *(float4*)(hout + (long)row * NDIM + c0) =
                make_float4(acc[r][0], acc[r][1], acc[r][2], acc[r][3]);
            s0 += acc[r][0]; q0 += acc[r][0] * acc[r][0];
            s1 += acc[r][1]; q1 += acc[r][1] * acc[r][1];
            s2 += acc[r][2]; q2 += acc[r][2] * acc[r][2];
            s3 += acc[r][3]; q3 += acc[r][3] * acc[r][3];
        }
    }
    redS[ty][c0] = s0; redS[ty][c0 + 1] = s1; redS[ty][c0 + 2] = s2; redS[ty][c0 + 3] = s3;
    redQ[ty][c0] = q0; redQ[ty][c0 + 1] = q1; redQ[ty][c0 + 2] = q2; redQ[ty][c0 + 3] = q3;
    __syncthreads();
    if (tid < NDIM) {
        float t = 0.f;
#pragma unroll
        for (int w = 0; w < 8; ++w) t += redS[w][tid];
        atomicAdd(&stats[tid], t);
    } else {
        int c = tid - NDIM;
        float t = 0.f;
#pragma unroll
        for (int w = 0; w < 8; ++w) t += redQ[w][c];
        atomicAdd(&stats[NDIM + c], t);
    }
}

// ---------------------------------------------------------------------------
// K4: out = relu(BN2(h2)) -> output dtype
// ---------------------------------------------------------------------------
template<bool BF>
__global__ __launch_bounds__(256) void bn2_out_kernel(
    const float* __restrict__ h2, const float* __restrict__ statsIn,
    const void* __restrict__ g, const void* __restrict__ beta,
    void* __restrict__ out, int M, const int* __restrict__ flag) {
    if ((*flag != 0) != BF) return;
    __shared__ float scaleL[NDIM];
    __shared__ float shiftL[NDIM];
    const int tid = threadIdx.x;
    if (tid < NDIM) {
        float s = statsIn[tid], q = statsIn[NDIM + tid];
        float invM = 1.0f / (float)M;
        float mean = s * invM;
        float var = fmaxf(q * invM - mean * mean, 0.0f) + 1e-5f;
        float sc = ld1<BF>(g, tid) * rsqrtf(var);
        scaleL[tid] = sc;
        shiftL[tid] = ld1<BF>(beta, tid) - mean * sc;
    }
    __syncthreads();

    const int n4 = M * NDIM / 4;
    for (int i = blockIdx.x * 256 + tid; i < n4; i += gridDim.x * 256) {
        int c = (i & 31) * 4;
        float4 hv = *(const float4*)(h2 + (long)i * 4);
        float o0 = fmaxf(hv.x * scaleL[c + 0] + shiftL[c + 0], 0.0f);
        float o1 = fmaxf(hv.y * scaleL[c + 1] + shiftL[c + 1], 0.0f);
        float o2 = fmaxf(hv.z * scaleL[c + 2] + shiftL[c + 2], 0.0f);
        float o3 = fmaxf(hv.w * scaleL[c + 3] + shiftL[c + 3], 0.0f);
        if (BF) {
            ushort4 o;
            o.x = f2bf(o0); o.y = f2bf(o1); o.z = f2bf(o2); o.w = f2bf(o3);
            *(ushort4*)((u16*)out + (long)i * 4) = o;
        } else {
            *(float4*)((float*)out + (long)i * 4) = make_float4(o0, o1, o2, o3);
        }
    }
}

extern "C" void kernel_launch(void* const* d_in, const int* in_sizes, int n_in,
                              void* d_out, int out_size, void* d_ws, size_t ws_size,
                              hipStream_t stream) {
    const void* x         = d_in[0];
    const int*  ei        = (const int*)d_in[1];
    const void* edge_attr = d_in[2];
    const void* eps_p     = d_in[3];
    const void* We        = d_in[4];
    const void* be        = d_in[5];
    const void* W1        = d_in[6];
    const void* b1        = d_in[7];
    const void* g1        = d_in[8];
    const void* beta1     = d_in[9];
    const void* W2        = d_in[10];
    const void* b2        = d_in[11];
    const void* g2        = d_in[12];
    const void* beta2     = d_in[13];

    const int N = in_sizes[0] / NDIM;          // 50000
    const int E = in_sizes[1] / 2;             // 800000
    const size_t nd = (size_t)N * NDIM;        // 6.4M

    // Common prefix layout
    float* agg    = (float*)d_ws;              // [nd]; reused as h2
    float* h1     = agg + nd;                  // [nd]
    float* stats1 = h1 + nd;                   // [256]
    float* stats2 = stats1 + 256;              // [256]
    int*   flag   = (int*)(stats2 + 256);      // [4]
    float* h2     = agg;

    // Big layout: CSR + EF after the prefix
    int* cntB     = flag + 4;
    int* curB     = cntB + N;
    int* rowB     = curB + N;
    int* eidxB    = rowB + N + 1;
    int* srcB     = eidxB + E;
    int* invB     = srcB + E;
    u16* EF       = (u16*)(invB + E);
    size_t required = (size_t)((char*)(EF + (size_t)E * NDIM) - (char*)d_ws);
    const bool big = ws_size >= required;

    // Fallback layout: CSR overlaid on h1 (dead until gemm1)
    int* cnt     = big ? cntB  : (int*)h1;
    int* cur     = big ? curB  : ((int*)h1 + N);
    int* row_ptr = big ? rowB  : ((int*)h1 + 2 * N);
    int* eidx    = big ? eidxB : ((int*)h1 + 3 * N + 1);
    int* src_s   = big ? srcB  : (eidx + E);
    int* inv_i   = big ? invB  : (eidx + 2 * E);   // unused in fallback compute

    detect_kernel<<<1, 64, 0, stream>>>(x, flag);
    hipMemsetAsync(stats1, 0, 512 * sizeof(float), stream);
    hipMemsetAsync(cnt, 0, 2 * (size_t)N * sizeof(int), stream);

    const int eblk = (E + 255) / 256;
    hist_kernel<<<eblk, 256, 0, stream>>>(ei, cnt, E);
    scan_kernel<<<1, 1024, 0, stream>>>(cnt, row_ptr, N);
    scatter2_kernel<<<eblk, 256, 0, stream>>>(ei, row_ptr, cur, eidx, src_s, inv_i, E);

    const int ablk = (N + 3) / 4;
    if (big) {
        const int ewaves = (E + 63) / 64;
        const int efblk = (ewaves + 3) / 4;
        ef_kernel<<<efblk, 256, 0, stream>>>((const u16*)edge_attr, (const u16*)We,
                                             (const u16*)be, inv_i, EF, E, flag);
        aggB_kernel<<<ablk, 256, 0, stream>>>(row_ptr, src_s, EF, (const u16*)x,
                                              agg, N, flag);
        // fp32-data fallback (dead when flag==1)
        agg_kernel<false><<<ablk, 256, 0, stream>>>(row_ptr, eidx, ei, edge_attr, x, We, be, agg, N, flag);
    } else {
        agg_kernel<true ><<<ablk, 256, 0, stream>>>(row_ptr, eidx, ei, edge_attr, x, We, be, agg, N, flag);
        agg_kernel<false><<<ablk, 256, 0, stream>>>(row_ptr, eidx, ei, edge_attr, x, We, be, agg, N, flag);
    }

    const int nblk = (N + 63) / 64;
    gemm1_kernel<false><<<nblk, 256, 0, stream>>>(x, agg, eps_p, W1, b1, h1, stats1, N, flag);
    gemm1_kernel<true ><<<nblk, 256, 0, stream>>>(x, agg, eps_p, W1, b1, h1, stats1, N, flag);

    gemm2_kernel<false><<<nblk, 256, 0, stream>>>(h1, stats1, g1, beta1, W2, b2, h2, stats2, N, flag);
    gemm2_kernel<true ><<<nblk, 256, 0, stream>>>(h1, stats1, g1, beta1, W2, b2, h2, stats2, N, flag);

    bn2_out_kernel<false><<<2048, 256, 0, stream>>>(h2, stats2, g2, beta2, d_out, N, flag);
    bn2_out_kernel<true ><<<2048, 256, 0, stream>>>(h2, stats2, g2, beta2, d_out, N, flag);
}

// Round 5
// 701.622 us; speedup vs baseline: 1.0857x; 1.0857x over previous
//
#include <hip/hip_runtime.h>
#include <hip/hip_bf16.h>

typedef unsigned short u16;

#define NDIM 128
#define EDIM 32

__device__ __forceinline__ float bf2f(u16 u) {
    union { unsigned int i; float f; } v; v.i = ((unsigned int)u) << 16; return v.f;
}
__device__ __forceinline__ u16 f2bf(float f) {
    __hip_bfloat16 h = __float2bfloat16(f);
    return *reinterpret_cast<u16*>(&h);
}
// wave-uniform broadcast from lane k (VALU pipe, not LDS)
__device__ __forceinline__ float rlane(float v, int k) {
    return __int_as_float(__builtin_amdgcn_readlane(__float_as_int(v), k));
}

template<bool BF>
__device__ __forceinline__ float ld1(const void* p, long i) {
    if (BF) return bf2f(((const u16*)p)[i]);
    return ((const float*)p)[i];
}
template<bool BF>
__device__ __forceinline__ float4 ld4(const void* p, long i) {
    if (BF) {
        ushort4 v = *(const ushort4*)((const u16*)p + i);
        return make_float4(bf2f(v.x), bf2f(v.y), bf2f(v.z), bf2f(v.w));
    }
    return *(const float4*)((const float*)p + i);
}

// ---------------------------------------------------------------------------
// K0: dtype detector (flag: 1 = bf16, 0 = fp32)
// ---------------------------------------------------------------------------
__global__ void detect_kernel(const void* __restrict__ x, int* __restrict__ flag) {
    __shared__ int cnt;
    if (threadIdx.x == 0) cnt = 0;
    __syncthreads();
    const u16* p = (const u16*)x;
    int crazy = 0;
    for (int i = threadIdx.x; i < 512; i += 64) {
        u16 v = p[2 * i];
        int e = (v >> 7) & 0xFF;
        if (e != 0 && (e < 100 || e > 150)) crazy++;
    }
    atomicAdd(&cnt, crazy);
    __syncthreads();
    if (threadIdx.x == 0) *flag = (cnt > 128) ? 0 : 1;
}

// ---------------------------------------------------------------------------
// CSR build: histogram -> scan -> scatter
// ---------------------------------------------------------------------------
__global__ __launch_bounds__(256) void hist_kernel(
    const int* __restrict__ ei, int* __restrict__ cnt, int E) {
    int e = blockIdx.x * 256 + threadIdx.x;
    if (e < E) atomicAdd(&cnt[ei[E + e]], 1);
}

__global__ __launch_bounds__(1024) void scan_kernel(
    const int* __restrict__ cnt, int* __restrict__ row_ptr, int N) {
    __shared__ int part[1024];
    const int t = threadIdx.x;
    const int chunk = (N + 1023) / 1024;
    const int lo = t * chunk;
    const int hi = min(lo + chunk, N);
    int s = 0;
    for (int i = lo; i < hi; ++i) s += cnt[i];
    part[t] = s;
    __syncthreads();
    for (int off = 1; off < 1024; off <<= 1) {
        int v = (t >= off) ? part[t - off] : 0;
        __syncthreads();
        part[t] += v;
        __syncthreads();
    }
    int run = (t == 0) ? 0 : part[t - 1];
    for (int i = lo; i < hi; ++i) { row_ptr[i] = run; run += cnt[i]; }
    if (t == 1023) row_ptr[N] = run;
}

__global__ __launch_bounds__(256) void scatter_kernel(
    const int* __restrict__ ei, const int* __restrict__ row_ptr,
    int* __restrict__ cur, int* __restrict__ eidx,
    int* __restrict__ src_sorted, int E) {
    int e = blockIdx.x * 256 + threadIdx.x;
    if (e < E) {
        int dst = ei[E + e];
        int slot = row_ptr[dst] + atomicAdd(&cur[dst], 1);
        eidx[slot] = e;
        src_sorted[slot] = ei[e];
    }
}

// ---------------------------------------------------------------------------
// K1: CSR aggregation, zero LDS ops in the hot loop.
// One wave per node (grid-stride). Lane owns dims {lane, lane+64}.
// We held in 64 VGPRs; edge attrs broadcast via v_readlane (VALU pipe).
// ---------------------------------------------------------------------------
template<bool BF>
__global__ __launch_bounds__(256) void agg_kernel(
    const int* __restrict__ row_ptr, const int* __restrict__ eidx,
    const int* __restrict__ src_sorted, const void* __restrict__ edge_attr,
    const void* __restrict__ x, const void* __restrict__ We,
    const void* __restrict__ be, float* __restrict__ agg, int N,
    const int* __restrict__ flag) {
    if ((*flag != 0) != BF) return;

    const int lane = threadIdx.x & 63;
    const int gwave = blockIdx.x * 4 + (threadIdx.x >> 6);
    const int nwaves = gridDim.x * 4;

    // We columns {lane, lane+64} in registers (64 VGPRs)
    float weA[EDIM], weB[EDIM];
#pragma unroll
    for (int k = 0; k < EDIM; ++k) {
        weA[k] = ld1<BF>(We, (long)k * NDIM + lane);
        weB[k] = ld1<BF>(We, (long)k * NDIM + 64 + lane);
    }
    const float be0 = ld1<BF>(be, lane);
    const float be1 = ld1<BF>(be, 64 + lane);

    for (int n = gwave; n < N; n += nwaves) {
        const int p0 = row_ptr[n], p1 = row_ptr[n + 1];
        float acc0 = 0.0f, acc1 = 0.0f;
        // prefetch edge 0
        int src = 0; float av = 0.0f;
        if (p0 < p1) {
            int eid = eidx[p0];
            src = src_sorted[p0];
            av = (lane < EDIM) ? ld1<BF>(edge_attr, (long)eid * EDIM + lane) : 0.0f;
        }
        for (int p = p0; p < p1; ++p) {
            const int csrc = src;
            const float cav = av;
            float xv0 = ld1<BF>(x, (long)csrc * NDIM + lane);
            float xv1 = ld1<BF>(x, (long)csrc * NDIM + 64 + lane);
            if (p + 1 < p1) {
                int eid = eidx[p + 1];
                src = src_sorted[p + 1];
                av = (lane < EDIM) ? ld1<BF>(edge_attr, (long)eid * EDIM + lane) : 0.0f;
            }
            float e0 = 0.0f, e1 = 0.0f;
#pragma unroll
            for (int k = 0; k < EDIM; ++k) {
                float ak = rlane(cav, k);     // VALU broadcast, no LDS
                e0 += ak * weA[k];
                e1 += ak * weB[k];
            }
            acc0 += fmaxf(e0 + be0, 0.0f) + xv0;
            acc1 += fmaxf(e1 + be1, 0.0f) + xv1;
        }
        agg[(long)n * NDIM + lane] = acc0;
        agg[(long)n * NDIM + 64 + lane] = acc1;
    }
}

// ---------------------------------------------------------------------------
// K2: h0 = (1+eps)*x + agg ; h1 = h0 @ W1 + b1 ; accumulate col sum/sumsq
// hT stride 132 (16B-aligned rows), K blocked by 4 -> ds_read_b128 broadcasts.
// ---------------------------------------------------------------------------
#define HSTR 132

template<bool BF>
__global__ __launch_bounds__(256) void gemm1_kernel(
    const void* __restrict__ x, const float* __restrict__ agg,
    const void* __restrict__ eps_p, const void* __restrict__ W,
    const void* __restrict__ b, float* __restrict__ hout,
    float* __restrict__ stats, int M, const int* __restrict__ flag) {
    if ((*flag != 0) != BF) return;
    __shared__ float hT[64 * HSTR];
    __shared__ float redS[8][NDIM];
    __shared__ float redQ[8][NDIM];

    const int tid = threadIdx.x;
    const int row0 = blockIdx.x * 64;
    const float onepeps = 1.0f + ld1<BF>(eps_p, 0);

#pragma unroll
    for (int i = 0; i < 8; ++i) {
        int idx = (tid + i * 256) * 4;
        int r = idx >> 7, c = idx & 127;
        int row = row0 + r;
        float v0 = 0.f, v1 = 0.f, v2 = 0.f, v3 = 0.f;
        if (row < M) {
            const float4 ag = *(const float4*)(agg + (long)row * NDIM + c);
            const float4 xv = ld4<BF>(x, (long)row * NDIM + c);
            v0 = onepeps * xv.x + ag.x;
            v1 = onepeps * xv.y + ag.y;
            v2 = onepeps * xv.z + ag.z;
            v3 = onepeps * xv.w + ag.w;
        }
        *(float4*)&hT[r * HSTR + c] = make_float4(v0, v1, v2, v3);
    }
    __syncthreads();

    const int tx = tid & 31, ty = tid >> 5;
    const int c0 = tx * 4;
    float acc[8][4];
#pragma unroll
    for (int j = 0; j < 4; ++j) {
        float bj = ld1<BF>(b, c0 + j);
#pragma unroll
        for (int r = 0; r < 8; ++r) acc[r][j] = bj;
    }

    for (int k0 = 0; k0 < NDIM; k0 += 4) {
        float4 w0 = ld4<BF>(W, (long)(k0 + 0) * NDIM + c0);
        float4 w1 = ld4<BF>(W, (long)(k0 + 1) * NDIM + c0);
        float4 w2 = ld4<BF>(W, (long)(k0 + 2) * NDIM + c0);
        float4 w3 = ld4<BF>(W, (long)(k0 + 3) * NDIM + c0);
#pragma unroll
        for (int r = 0; r < 8; ++r) {
            float4 h = *(const float4*)&hT[(ty * 8 + r) * HSTR + k0];
            acc[r][0] += h.x * w0.x + h.y * w1.x + h.z * w2.x + h.w * w3.x;
            acc[r][1] += h.x * w0.y + h.y * w1.y + h.z * w2.y + h.w * w3.y;
            acc[r][2] += h.x * w0.z + h.y * w1.z + h.z * w2.z + h.w * w3.z;
            acc[r][3] += h.x * w0.w + h.y * w1.w + h.z * w2.w + h.w * w3.w;
        }
    }

    float s0 = 0.f, s1 = 0.f, s2 = 0.f, s3 = 0.f;
    float q0 = 0.f, q1 = 0.f, q2 = 0.f, q3 = 0.f;
#pragma unroll
    for (int r = 0; r < 8; ++r) {
        int row = row0 + ty * 8 + r;
        if (row < M) {
            *(float4*)(hout + (long)row * NDIM + c0) =
                make_float4(acc[r][0], acc[r][1], acc[r][2], acc[r][3]);
            s0 += acc[r][0]; q0 += acc[r][0] * acc[r][0];
            s1 += acc[r][1]; q1 += acc[r][1] * acc[r][1];
            s2 += acc[r][2]; q2 += acc[r][2] * acc[r][2];
            s3 += acc[r][3]; q3 += acc[r][3] * acc[r][3];
        }
    }
    redS[ty][c0] = s0; redS[ty][c0 + 1] = s1; redS[ty][c0 + 2] = s2; redS[ty][c0 + 3] = s3;
    redQ[ty][c0] = q0; redQ[ty][c0 + 1] = q1; redQ[ty][c0 + 2] = q2; redQ[ty][c0 + 3] = q3;
    __syncthreads();
    if (tid < NDIM) {
        float t = 0.f;
#pragma unroll
        for (int w = 0; w < 8; ++w) t += redS[w][tid];
        atomicAdd(&stats[tid], t);
    } else {
        int c = tid - NDIM;
        float t = 0.f;
#pragma unroll
        for (int w = 0; w < 8; ++w) t += redQ[w][c];
        atomicAdd(&stats[NDIM + c], t);
    }
}

// ---------------------------------------------------------------------------
// K3: a = relu(BN1(h1)) ; h2 = a @ W2 + b2 ; accumulate col sum/sumsq
// ---------------------------------------------------------------------------
template<bool BF>
__global__ __launch_bounds__(256) void gemm2_kernel(
    const float* __restrict__ h1, const float* __restrict__ statsIn,
    const void* __restrict__ g, const void* __restrict__ beta,
    const void* __restrict__ W, const void* __restrict__ b,
    float* __restrict__ hout, float* __restrict__ stats, int M,
    const int* __restrict__ flag) {
    if ((*flag != 0) != BF) return;
    __shared__ float hT[64 * HSTR];
    __shared__ float redS[8][NDIM];
    __shared__ float redQ[8][NDIM];
    __shared__ float scaleL[NDIM];
    __shared__ float shiftL[NDIM];

    const int tid = threadIdx.x;
    const int row0 = blockIdx.x * 64;

    if (tid < NDIM) {
        float s = statsIn[tid], q = statsIn[NDIM + tid];
        float invM = 1.0f / (float)M;
        float mean = s * invM;
        float var = fmaxf(q * invM - mean * mean, 0.0f) + 1e-5f;
        float sc = ld1<BF>(g, tid) * rsqrtf(var);
        scaleL[tid] = sc;
        shiftL[tid] = ld1<BF>(beta, tid) - mean * sc;
    }
    __syncthreads();

#pragma unroll
    for (int i = 0; i < 8; ++i) {
        int idx = (tid + i * 256) * 4;
        int r = idx >> 7, c = idx & 127;
        int row = row0 + r;
        float v0 = 0.f, v1 = 0.f, v2 = 0.f, v3 = 0.f;
        if (row < M) {
            const float4 hv = *(const float4*)(h1 + (long)row * NDIM + c);
            v0 = fmaxf(hv.x * scaleL[c + 0] + shiftL[c + 0], 0.0f);
            v1 = fmaxf(hv.y * scaleL[c + 1] + shiftL[c + 1], 0.0f);
            v2 = fmaxf(hv.z * scaleL[c + 2] + shiftL[c + 2], 0.0f);
            v3 = fmaxf(hv.w * scaleL[c + 3] + shiftL[c + 3], 0.0f);
        }
        *(float4*)&hT[r * HSTR + c] = make_float4(v0, v1, v2, v3);
    }
    __syncthreads();

    const int tx = tid & 31, ty = tid >> 5;
    const int c0 = tx * 4;
    float acc[8][4];
#pragma unroll
    for (int j = 0; j < 4; ++j) {
        float bj = ld1<BF>(b, c0 + j);
#pragma unroll
        for (int r = 0; r < 8; ++r) acc[r][j] = bj;
    }

    for (int k0 = 0; k0 < NDIM; k0 += 4) {
        float4 w0 = ld4<BF>(W, (long)(k0 + 0) * NDIM + c0);
        float4 w1 = ld4<BF>(W, (long)(k0 + 1) * NDIM + c0);
        float4 w2 = ld4<BF>(W, (long)(k0 + 2) * NDIM + c0);
        float4 w3 = ld4<BF>(W, (long)(k0 + 3) * NDIM + c0);
#pragma unroll
        for (int r = 0; r < 8; ++r) {
            float4 h = *(const float4*)&hT[(ty * 8 + r) * HSTR + k0];
            acc[r][0] += h.x * w0.x + h.y * w1.x + h.z * w2.x + h.w * w3.x;
            acc[r][1] += h.x * w0.y + h.y * w1.y + h.z * w2.y + h.w * w3.y;
            acc[r][2] += h.x * w0.z + h.y * w1.z + h.z * w2.z + h.w * w3.z;
            acc[r][3] += h.x * w0.w + h.y * w1.w + h.z * w2.w + h.w * w3.w;
        }
    }

    float s0 = 0.f, s1 = 0.f, s2 = 0.f, s3 = 0.f;
    float q0 = 0.f, q1 = 0.f, q2 = 0.f, q3 = 0.f;
#pragma unroll
    for (int r = 0; r < 8; ++r) {
        int row = row0 + ty * 8 + r;
        if (row < M) {
            *(float4*)(hout + (long)row * NDIM + c0) =
                make_float4(acc[r][0], acc[r][1], acc[r][2], acc[r][3]);
            s0 += acc[r][0]; q0 += acc[r][0] * acc[r][0];
            s1 += acc[r][1]; q1 += acc[r][1] * acc[r][1];
            s2 += acc[r][2]; q2 += acc[r][2] * acc[r][2];
            s3 += acc[r][3]; q3 += acc[r][3] * acc[r][3];
        }
    }
    redS[ty][c0] = s0; redS[ty][c0 + 1] = s1; redS[ty][c0 + 2] = s2; redS[ty][c0 + 3] = s3;
    redQ[ty][c0] = q0; redQ[ty][c0 + 1] = q1; redQ[ty][c0 + 2] = q2; redQ[ty][c0 + 3] = q3;
    __syncthreads();
    if (tid < NDIM) {
        float t = 0.f;
#pragma unroll
        for (int w = 0; w < 8; ++w) t += redS[w][tid];
        atomicAdd(&stats[tid], t);
    } else {
        int c = tid - NDIM;
        float t = 0.f;
#pragma unroll
        for (int w = 0; w < 8; ++w) t += redQ[w][c];
        atomicAdd(&stats[NDIM + c], t);
    }
}

// ---------------------------------------------------------------------------
// K4: out = relu(BN2(h2)) -> output dtype
// ---------------------------------------------------------------------------
template<bool BF>
__global__ __launch_bounds__(256) void bn2_out_kernel(
    const float* __restrict__ h2, const float* __restrict__ statsIn,
    const void* __restrict__ g, const void* __restrict__ beta,
    void* __restrict__ out, int M, const int* __restrict__ flag) {
    if ((*flag != 0) != BF) return;
    __shared__ float scaleL[NDIM];
    __shared__ float shiftL[NDIM];
    const int tid = threadIdx.x;
    if (tid < NDIM) {
        float s = statsIn[tid], q = statsIn[NDIM + tid];
        float invM = 1.0f / (float)M;
        float mean = s * invM;
        float var = fmaxf(q * invM - mean * mean, 0.0f) + 1e-5f;
        float sc = ld1<BF>(g, tid) * rsqrtf(var);
        scaleL[tid] = sc;
        shiftL[tid] = ld1<BF>(beta, tid) - mean * sc;
    }
    __syncthreads();

    const int n4 = M * NDIM / 4;
    for (int i = blockIdx.x * 256 + tid; i < n4; i += gridDim.x * 256) {
        int c = (i & 31) * 4;
        float4 hv = *(const float4*)(h2 + (long)i * 4);
        float o0 = fmaxf(hv.x * scaleL[c + 0] + shiftL[c + 0], 0.0f);
        float o1 = fmaxf(hv.y * scaleL[c + 1] + shiftL[c + 1], 0.0f);
        float o2 = fmaxf(hv.z * scaleL[c + 2] + shiftL[c + 2], 0.0f);
        float o3 = fmaxf(hv.w * scaleL[c + 3] + shiftL[c + 3], 0.0f);
        if (BF) {
            ushort4 o;
            o.x = f2bf(o0); o.y = f2bf(o1); o.z = f2bf(o2); o.w = f2bf(o3);
            *(ushort4*)((u16*)out + (long)i * 4) = o;
        } else {
            *(float4*)((float*)out + (long)i * 4) = make_float4(o0, o1, o2, o3);
        }
    }
}

extern "C" void kernel_launch(void* const* d_in, const int* in_sizes, int n_in,
                              void* d_out, int out_size, void* d_ws, size_t ws_size,
                              hipStream_t stream) {
    const void* x         = d_in[0];
    const int*  ei        = (const int*)d_in[1];
    const void* edge_attr = d_in[2];
    const void* eps_p     = d_in[3];
    const void* We        = d_in[4];
    const void* be        = d_in[5];
    const void* W1        = d_in[6];
    const void* b1        = d_in[7];
    const void* g1        = d_in[8];
    const void* beta1     = d_in[9];
    const void* W2        = d_in[10];
    const void* b2        = d_in[11];
    const void* g2        = d_in[12];
    const void* beta2     = d_in[13];

    const int N = in_sizes[0] / NDIM;          // 50000
    const int E = in_sizes[1] / 2;             // 800000
    const size_t nd = (size_t)N * NDIM;        // 6.4M

    float* agg    = (float*)d_ws;              // [nd]; reused as h2
    float* h1     = agg + nd;                  // [nd]
    float* stats1 = h1 + nd;                   // [256]
    float* stats2 = stats1 + 256;              // [256]
    int*   flag   = (int*)(stats2 + 256);      // [4]
    float* h2     = agg;

    // CSR scratch overlaid on h1 (dead until gemm1 writes h1)
    int* cnt     = (int*)h1;                   // [N]
    int* cur     = cnt + N;                    // [N]
    int* row_ptr = cur + N;                    // [N+1]
    int* eidx    = row_ptr + N + 1;            // [E]
    int* src_s   = eidx + E;                   // [E]

    detect_kernel<<<1, 64, 0, stream>>>(x, flag);
    hipMemsetAsync(stats1, 0, 512 * sizeof(float), stream);
    hipMemsetAsync(cnt, 0, 2 * (size_t)N * sizeof(int), stream);

    const int eblk = (E + 255) / 256;
    hist_kernel<<<eblk, 256, 0, stream>>>(ei, cnt, E);
    scan_kernel<<<1, 1024, 0, stream>>>(cnt, row_ptr, N);
    scatter_kernel<<<eblk, 256, 0, stream>>>(ei, row_ptr, cur, eidx, src_s, E);

    agg_kernel<true ><<<1024, 256, 0, stream>>>(row_ptr, eidx, src_s, edge_attr, x, We, be, agg, N, flag);
    agg_kernel<false><<<1024, 256, 0, stream>>>(row_ptr, eidx, src_s, edge_attr, x, We, be, agg, N, flag);

    const int nblk = (N + 63) / 64;
    gemm1_kernel<false><<<nblk, 256, 0, stream>>>(x, agg, eps_p, W1, b1, h1, stats1, N, flag);
    gemm1_kernel<true ><<<nblk, 256, 0, stream>>>(x, agg, eps_p, W1, b1, h1, stats1, N, flag);

    gemm2_kernel<false><<<nblk, 256, 0, stream>>>(h1, stats1, g1, beta1, W2, b2, h2, stats2, N, flag);
    gemm2_kernel<true ><<<nblk, 256, 0, stream>>>(h1, stats1, g1, beta1, W2, b2, h2, stats2, N, flag);

    bn2_out_kernel<false><<<2048, 256, 0, stream>>>(h2, stats2, g2, beta2, d_out, N, flag);
    bn2_out_kernel<true ><<<2048, 256, 0, stream>>>(h2, stats2, g2, beta2, d_out, N, flag);
}

// Round 6
// 675.880 us; speedup vs baseline: 1.1271x; 1.0381x over previous
//
#include <hip/hip_runtime.h>
#include <hip/hip_bf16.h>

typedef unsigned short u16;
typedef __attribute__((ext_vector_type(8))) short bf16x8;
typedef __attribute__((ext_vector_type(4))) float f32x4;

#define NDIM 128
#define EDIM 32
#define WT_STR 40    // agg We^T LDS stride (u16): 2-way bank conflicts only
#define HSTR 136     // gemm LDS stride (u16): 16B aligned, 2-way banks

__device__ __forceinline__ float bf2f(u16 u) {
    union { unsigned int i; float f; } v; v.i = ((unsigned int)u) << 16; return v.f;
}
__device__ __forceinline__ u16 f2bf(float f) {
    __hip_bfloat16 h = __float2bfloat16(f);
    return *reinterpret_cast<u16*>(&h);
}
__device__ __forceinline__ float rlane(float v, int k) {
    return __int_as_float(__builtin_amdgcn_readlane(__float_as_int(v), k));
}

template<bool BF>
__device__ __forceinline__ float ld1(const void* p, long i) {
    if (BF) return bf2f(((const u16*)p)[i]);
    return ((const float*)p)[i];
}
template<bool BF>
__device__ __forceinline__ float4 ld4(const void* p, long i) {
    if (BF) {
        ushort4 v = *(const ushort4*)((const u16*)p + i);
        return make_float4(bf2f(v.x), bf2f(v.y), bf2f(v.z), bf2f(v.w));
    }
    return *(const float4*)((const float*)p + i);
}

// ---------------------------------------------------------------------------
// K0: dtype detector (flag: 1 = bf16, 0 = fp32)
// ---------------------------------------------------------------------------
__global__ void detect_kernel(const void* __restrict__ x, int* __restrict__ flag) {
    __shared__ int cnt;
    if (threadIdx.x == 0) cnt = 0;
    __syncthreads();
    const u16* p = (const u16*)x;
    int crazy = 0;
    for (int i = threadIdx.x; i < 512; i += 64) {
        u16 v = p[2 * i];
        int e = (v >> 7) & 0xFF;
        if (e != 0 && (e < 100 || e > 150)) crazy++;
    }
    atomicAdd(&cnt, crazy);
    __syncthreads();
    if (threadIdx.x == 0) *flag = (cnt > 128) ? 0 : 1;
}

// ---------------------------------------------------------------------------
// CSR build: histogram -> scan -> scatter
// ---------------------------------------------------------------------------
__global__ __launch_bounds__(256) void hist_kernel(
    const int* __restrict__ ei, int* __restrict__ cnt, int E) {
    int e = blockIdx.x * 256 + threadIdx.x;
    if (e < E) atomicAdd(&cnt[ei[E + e]], 1);
}

__global__ __launch_bounds__(1024) void scan_kernel(
    const int* __restrict__ cnt, int* __restrict__ row_ptr, int N) {
    __shared__ int part[1024];
    const int t = threadIdx.x;
    const int chunk = (N + 1023) / 1024;
    const int lo = t * chunk;
    const int hi = min(lo + chunk, N);
    int s = 0;
    for (int i = lo; i < hi; ++i) s += cnt[i];
    part[t] = s;
    __syncthreads();
    for (int off = 1; off < 1024; off <<= 1) {
        int v = (t >= off) ? part[t - off] : 0;
        __syncthreads();
        part[t] += v;
        __syncthreads();
    }
    int run = (t == 0) ? 0 : part[t - 1];
    for (int i = lo; i < hi; ++i) { row_ptr[i] = run; run += cnt[i]; }
    if (t == 1023) row_ptr[N] = run;
}

__global__ __launch_bounds__(256) void scatter_kernel(
    const int* __restrict__ ei, const int* __restrict__ row_ptr,
    int* __restrict__ cur, int* __restrict__ eidx,
    int* __restrict__ src_sorted, int E) {
    int e = blockIdx.x * 256 + threadIdx.x;
    if (e < E) {
        int dst = ei[E + e];
        int slot = row_ptr[dst] + atomicAdd(&cur[dst], 1);
        eidx[slot] = e;
        src_sorted[slot] = ei[e];
    }
}

// ---------------------------------------------------------------------------
// K1 (bf16): CSR aggregation with fused MFMA edge-embed.
// One wave per node (grid-stride). Per 16-edge group:
//   A[m=edge(lane&15)][k=quad*8+j] = attr row (16B gather/lane)
//   B[k=quad*8+j][n=dim(lane&15)]  = We^T from LDS (ds_read_b128)
//   D = mfma_16x16x32(A,B,C=bias): lane holds col=dim, rows=4 edges
//   -> relu + per-reg validity mask -> part[8]; shfl_xor cross-quad reduce.
// x-gather: quad q handles edges q,q+4,q+8,q+12; lane owns dims lane16*8..+7,
// exchanged through LDS xsumQ at node end.
// ---------------------------------------------------------------------------
__global__ __launch_bounds__(256) void agg_mfma_kernel(
    const int* __restrict__ row_ptr, const int* __restrict__ eidx,
    const int* __restrict__ src_sorted, const u16* __restrict__ edge_attr,
    const u16* __restrict__ x, const u16* __restrict__ We,
    const u16* __restrict__ be, float* __restrict__ agg, int N,
    const int* __restrict__ flag) {
    if (*flag != 1) return;
    __shared__ u16 Wt[NDIM * WT_STR];          // Wt[d][k] = We[k][d]
    __shared__ float xsumQ[4][4][NDIM];        // [wave][quad][dim]

    for (int i = threadIdx.x; i < NDIM * EDIM; i += 256) {
        int k = i >> 7, d = i & 127;           // coalesced read of We[k][d]
        Wt[d * WT_STR + k] = We[i];
    }
    __syncthreads();

    const int lane = threadIdx.x & 63;
    const int wid = threadIdx.x >> 6;
    const int q = lane >> 4, l16 = lane & 15;

    float bias[8];
#pragma unroll
    for (int nt = 0; nt < 8; ++nt) bias[nt] = bf2f(be[nt * 16 + l16]);

    const int gwave = blockIdx.x * 4 + wid;
    const int nwaves = gridDim.x * 4;

    for (int n = gwave; n < N; n += nwaves) {
        const int p0 = row_ptr[n], p1 = row_ptr[n + 1];
        float part[8];
#pragma unroll
        for (int nt = 0; nt < 8; ++nt) part[nt] = 0.0f;
        float xa[8];
#pragma unroll
        for (int j = 0; j < 8; ++j) xa[j] = 0.0f;

        for (int base = p0; base < p1; base += 16) {
            const int cnt = min(16, p1 - base);
            // x-gather: quad-parallel, 8 dims per lane
            for (int t = q; t < cnt; t += 4) {
                int s = src_sorted[base + t];
                const u16* xr = x + (long)s * NDIM + l16 * 8;
                ushort4 a = *(const ushort4*)xr;
                ushort4 b = *(const ushort4*)(xr + 4);
                xa[0] += bf2f(a.x); xa[1] += bf2f(a.y);
                xa[2] += bf2f(a.z); xa[3] += bf2f(a.w);
                xa[4] += bf2f(b.x); xa[5] += bf2f(b.y);
                xa[6] += bf2f(b.z); xa[7] += bf2f(b.w);
            }
            // MFMA edge embed for this 16-edge group
            int slotA = base + l16;
            int eid = eidx[min(slotA, p1 - 1)];
            bf16x8 afrag = *(const bf16x8*)(edge_attr + (long)eid * EDIM + q * 8);
#pragma unroll
            for (int nt = 0; nt < 8; ++nt) {
                bf16x8 bfrag = *(const bf16x8*)&Wt[(nt * 16 + l16) * WT_STR + q * 8];
                f32x4 c = {bias[nt], bias[nt], bias[nt], bias[nt]};
                c = __builtin_amdgcn_mfma_f32_16x16x32_bf16(afrag, bfrag, c, 0, 0, 0);
#pragma unroll
                for (int r = 0; r < 4; ++r) {
                    if (q * 4 + r < cnt) part[nt] += fmaxf(c[r], 0.0f);
                }
            }
        }
        // cross-quad reduce of MFMA parts (all lanes end with totals)
#pragma unroll
        for (int nt = 0; nt < 8; ++nt) {
            part[nt] += __shfl_xor(part[nt], 16);
            part[nt] += __shfl_xor(part[nt], 32);
        }
        // exchange x partials through LDS (per-wave slice, no barrier needed)
        *(float4*)&xsumQ[wid][q][l16 * 8 + 0] = make_float4(xa[0], xa[1], xa[2], xa[3]);
        *(float4*)&xsumQ[wid][q][l16 * 8 + 4] = make_float4(xa[4], xa[5], xa[6], xa[7]);
        // quad q writes dim tiles {2q, 2q+1}
#pragma unroll
        for (int j = 0; j < 2; ++j) {
            int nt = 2 * q + j;
            int d = nt * 16 + l16;
            float xs = xsumQ[wid][0][d] + xsumQ[wid][1][d] +
                       xsumQ[wid][2][d] + xsumQ[wid][3][d];
            agg[(long)n * NDIM + d] = part[nt] + xs;
        }
    }
}

// ---------------------------------------------------------------------------
// K1 (fp32 fallback): R5 readlane VALU aggregation
// ---------------------------------------------------------------------------
__global__ __launch_bounds__(256) void agg_f32_kernel(
    const int* __restrict__ row_ptr, const int* __restrict__ eidx,
    const int* __restrict__ src_sorted, const void* __restrict__ edge_attr,
    const void* __restrict__ x, const void* __restrict__ We,
    const void* __restrict__ be, float* __restrict__ agg, int N,
    const int* __restrict__ flag) {
    if (*flag != 0) return;
    const int lane = threadIdx.x & 63;
    const int gwave = blockIdx.x * 4 + (threadIdx.x >> 6);
    const int nwaves = gridDim.x * 4;

    float weA[EDIM], weB[EDIM];
#pragma unroll
    for (int k = 0; k < EDIM; ++k) {
        weA[k] = ld1<false>(We, (long)k * NDIM + lane);
        weB[k] = ld1<false>(We, (long)k * NDIM + 64 + lane);
    }
    const float be0 = ld1<false>(be, lane);
    const float be1 = ld1<false>(be, 64 + lane);

    for (int n = gwave; n < N; n += nwaves) {
        const int p0 = row_ptr[n], p1 = row_ptr[n + 1];
        float acc0 = 0.0f, acc1 = 0.0f;
        int src = 0; float av = 0.0f;
        if (p0 < p1) {
            int eid = eidx[p0];
            src = src_sorted[p0];
            av = (lane < EDIM) ? ld1<false>(edge_attr, (long)eid * EDIM + lane) : 0.0f;
        }
        for (int p = p0; p < p1; ++p) {
            const int csrc = src;
            const float cav = av;
            float xv0 = ld1<false>(x, (long)csrc * NDIM + lane);
            float xv1 = ld1<false>(x, (long)csrc * NDIM + 64 + lane);
            if (p + 1 < p1) {
                int eid = eidx[p + 1];
                src = src_sorted[p + 1];
                av = (lane < EDIM) ? ld1<false>(edge_attr, (long)eid * EDIM + lane) : 0.0f;
            }
            float e0 = 0.0f, e1 = 0.0f;
#pragma unroll
            for (int k = 0; k < EDIM; ++k) {
                float ak = rlane(cav, k);
                e0 += ak * weA[k];
                e1 += ak * weB[k];
            }
            acc0 += fmaxf(e0 + be0, 0.0f) + xv0;
            acc1 += fmaxf(e1 + be1, 0.0f) + xv1;
        }
        agg[(long)n * NDIM + lane] = acc0;
        agg[(long)n * NDIM + 64 + lane] = acc1;
    }
}

// ---------------------------------------------------------------------------
// Shared MFMA GEMM core pieces.
// Block: 64 rows x 128 cols, 4 waves; wave w owns rows w*16..w*16+15.
// h staged as split bf16 (hi+lo) -> 2 MFMAs per tile (fp32-accurate).
// Stats: per-lane col partials -> shfl_xor quad reduce -> LDS -> atomicAdd.
// ---------------------------------------------------------------------------
template<bool BF>
__device__ __forceinline__ void stage_Wt(const void* W, u16* Wt) {
    for (int i = threadIdx.x; i < NDIM * NDIM / 4; i += 256) {
        int idx = i * 4;
        int k = idx >> 7, c = idx & 127;
        if (BF) {
            ushort4 wv = *(const ushort4*)((const u16*)W + (long)k * NDIM + c);
            Wt[(c + 0) * HSTR + k] = wv.x;
            Wt[(c + 1) * HSTR + k] = wv.y;
            Wt[(c + 2) * HSTR + k] = wv.z;
            Wt[(c + 3) * HSTR + k] = wv.w;
        } else {
            float4 wv = ld4<false>(W, (long)k * NDIM + c);
            Wt[(c + 0) * HSTR + k] = f2bf(wv.x);
            Wt[(c + 1) * HSTR + k] = f2bf(wv.y);
            Wt[(c + 2) * HSTR + k] = f2bf(wv.z);
            Wt[(c + 3) * HSTR + k] = f2bf(wv.w);
        }
    }
}

__device__ __forceinline__ void split_store(u16* hHi, u16* hLo, int r, int c, float4 h) {
    ushort4 hi, lo;
    hi.x = f2bf(h.x); lo.x = f2bf(h.x - bf2f(hi.x));
    hi.y = f2bf(h.y); lo.y = f2bf(h.y - bf2f(hi.y));
    hi.z = f2bf(h.z); lo.z = f2bf(h.z - bf2f(hi.z));
    hi.w = f2bf(h.w); lo.w = f2bf(h.w - bf2f(hi.w));
    *(ushort4*)&hHi[r * HSTR + c] = hi;
    *(ushort4*)&hLo[r * HSTR + c] = lo;
}

// K2: h0 = (1+eps)*x + agg ; h1 = h0 @ W1 + b1 ; col stats
template<bool BF>
__global__ __launch_bounds__(256) void gemm1_kernel(
    const void* __restrict__ x, const float* __restrict__ agg,
    const void* __restrict__ eps_p, const void* __restrict__ W,
    const void* __restrict__ b, float* __restrict__ hout,
    float* __restrict__ stats, int M, const int* __restrict__ flag) {
    if ((*flag != 0) != BF) return;
    __shared__ u16 hHi[64 * HSTR];
    __shared__ u16 hLo[64 * HSTR];
    __shared__ u16 Wt[NDIM * HSTR];
    __shared__ float redS[4][NDIM];
    __shared__ float redQ[4][NDIM];

    const int tid = threadIdx.x;
    const int row0 = blockIdx.x * 64;
    const float onepeps = 1.0f + ld1<BF>(eps_p, 0);

    stage_Wt<BF>(W, Wt);
#pragma unroll
    for (int i = 0; i < 8; ++i) {
        int idx = (tid + i * 256) * 4;
        int r = idx >> 7, c = idx & 127;
        int row = row0 + r;
        float4 h = make_float4(0.f, 0.f, 0.f, 0.f);
        if (row < M) {
            float4 ag = *(const float4*)(agg + (long)row * NDIM + c);
            float4 xv = ld4<BF>(x, (long)row * NDIM + c);
            h = make_float4(onepeps * xv.x + ag.x, onepeps * xv.y + ag.y,
                            onepeps * xv.z + ag.z, onepeps * xv.w + ag.w);
        }
        split_store(hHi, hLo, r, c, h);
    }
    __syncthreads();

    const int lane = tid & 63, w = tid >> 6;
    const int q = lane >> 4, l16 = lane & 15;

    f32x4 acc[8];
#pragma unroll
    for (int nt = 0; nt < 8; ++nt) {
        float bj = ld1<BF>(b, nt * 16 + l16);
        acc[nt] = (f32x4){bj, bj, bj, bj};
    }
#pragma unroll
    for (int ks = 0; ks < 4; ++ks) {
        bf16x8 aHi = *(const bf16x8*)&hHi[(w * 16 + l16) * HSTR + ks * 32 + q * 8];
        bf16x8 aLo = *(const bf16x8*)&hLo[(w * 16 + l16) * HSTR + ks * 32 + q * 8];
#pragma unroll
        for (int nt = 0; nt < 8; ++nt) {
            bf16x8 bf = *(const bf16x8*)&Wt[(nt * 16 + l16) * HSTR + ks * 32 + q * 8];
            acc[nt] = __builtin_amdgcn_mfma_f32_16x16x32_bf16(aHi, bf, acc[nt], 0, 0, 0);
            acc[nt] = __builtin_amdgcn_mfma_f32_16x16x32_bf16(aLo, bf, acc[nt], 0, 0, 0);
        }
    }

    // store + stats
#pragma unroll
    for (int nt = 0; nt < 8; ++nt) {
        float s = 0.f, qs = 0.f;
#pragma unroll
        for (int r = 0; r < 4; ++r) {
            int row = row0 + w * 16 + q * 4 + r;
            if (row < M) {
                float v = acc[nt][r];
                hout[(long)row * NDIM + nt * 16 + l16] = v;
                s += v; qs += v * v;
            }
        }
        s += __shfl_xor(s, 16);  s += __shfl_xor(s, 32);
        qs += __shfl_xor(qs, 16); qs += __shfl_xor(qs, 32);
        if (nt == 2 * q || nt == 2 * q + 1) {
            redS[w][nt * 16 + l16] = s;
            redQ[w][nt * 16 + l16] = qs;
        }
    }
    __syncthreads();
    if (tid < NDIM) {
        atomicAdd(&stats[tid], redS[0][tid] + redS[1][tid] + redS[2][tid] + redS[3][tid]);
    } else {
        int c = tid - NDIM;
        atomicAdd(&stats[NDIM + c], redQ[0][c] + redQ[1][c] + redQ[2][c] + redQ[3][c]);
    }
}

// K3: a = relu(BN1(h1)) ; h2 = a @ W2 + b2 ; col stats
template<bool BF>
__global__ __launch_bounds__(256) void gemm2_kernel(
    const float* __restrict__ h1, const float* __restrict__ statsIn,
    const void* __restrict__ g, const void* __restrict__ beta,
    const void* __restrict__ W, const void* __restrict__ b,
    float* __restrict__ hout, float* __restrict__ stats, int M,
    const int* __restrict__ flag) {
    if ((*flag != 0) != BF) return;
    __shared__ u16 hHi[64 * HSTR];
    __shared__ u16 hLo[64 * HSTR];
    __shared__ u16 Wt[NDIM * HSTR];
    __shared__ float redS[4][NDIM];
    __shared__ float redQ[4][NDIM];
    __shared__ float scaleL[NDIM];
    __shared__ float shiftL[NDIM];

    const int tid = threadIdx.x;
    const int row0 = blockIdx.x * 64;

    if (tid < NDIM) {
        float s = statsIn[tid], qv = statsIn[NDIM + tid];
        float invM = 1.0f / (float)M;
        float mean = s * invM;
        float var = fmaxf(qv * invM - mean * mean, 0.0f) + 1e-5f;
        float sc = ld1<BF>(g, tid) * rsqrtf(var);
        scaleL[tid] = sc;
        shiftL[tid] = ld1<BF>(beta, tid) - mean * sc;
    }
    stage_Wt<BF>(W, Wt);
    __syncthreads();

#pragma unroll
    for (int i = 0; i < 8; ++i) {
        int idx = (tid + i * 256) * 4;
        int r = idx >> 7, c = idx & 127;
        int row = row0 + r;
        float4 h = make_float4(0.f, 0.f, 0.f, 0.f);
        if (row < M) {
            float4 hv = *(const float4*)(h1 + (long)row * NDIM + c);
            h.x = fmaxf(hv.x * scaleL[c + 0] + shiftL[c + 0], 0.0f);
            h.y = fmaxf(hv.y * scaleL[c + 1] + shiftL[c + 1], 0.0f);
            h.z = fmaxf(hv.z * scaleL[c + 2] + shiftL[c + 2], 0.0f);
            h.w = fmaxf(hv.w * scaleL[c + 3] + shiftL[c + 3], 0.0f);
        }
        split_store(hHi, hLo, r, c, h);
    }
    __syncthreads();

    const int lane = tid & 63, w = tid >> 6;
    const int q = lane >> 4, l16 = lane & 15;

    f32x4 acc[8];
#pragma unroll
    for (int nt = 0; nt < 8; ++nt) {
        float bj = ld1<BF>(b, nt * 16 + l16);
        acc[nt] = (f32x4){bj, bj, bj, bj};
    }
#pragma unroll
    for (int ks = 0; ks < 4; ++ks) {
        bf16x8 aHi = *(const bf16x8*)&hHi[(w * 16 + l16) * HSTR + ks * 32 + q * 8];
        bf16x8 aLo = *(const bf16x8*)&hLo[(w * 16 + l16) * HSTR + ks * 32 + q * 8];
#pragma unroll
        for (int nt = 0; nt < 8; ++nt) {
            bf16x8 bf = *(const bf16x8*)&Wt[(nt * 16 + l16) * HSTR + ks * 32 + q * 8];
            acc[nt] = __builtin_amdgcn_mfma_f32_16x16x32_bf16(aHi, bf, acc[nt], 0, 0, 0);
            acc[nt] = __builtin_amdgcn_mfma_f32_16x16x32_bf16(aLo, bf, acc[nt], 0, 0, 0);
        }
    }

#pragma unroll
    for (int nt = 0; nt < 8; ++nt) {
        float s = 0.f, qs = 0.f;
#pragma unroll
        for (int r = 0; r < 4; ++r) {
            int row = row0 + w * 16 + q * 4 + r;
            if (row < M) {
                float v = acc[nt][r];
                hout[(long)row * NDIM + nt * 16 + l16] = v;
                s += v; qs += v * v;
            }
        }
        s += __shfl_xor(s, 16);  s += __shfl_xor(s, 32);
        qs += __shfl_xor(qs, 16); qs += __shfl_xor(qs, 32);
        if (nt == 2 * q || nt == 2 * q + 1) {
            redS[w][nt * 16 + l16] = s;
            redQ[w][nt * 16 + l16] = qs;
        }
    }
    __syncthreads();
    if (tid < NDIM) {
        atomicAdd(&stats[tid], redS[0][tid] + redS[1][tid] + redS[2][tid] + redS[3][tid]);
    } else {
        int c = tid - NDIM;
        atomicAdd(&stats[NDIM + c], redQ[0][c] + redQ[1][c] + redQ[2][c] + redQ[3][c]);
    }
}

// ---------------------------------------------------------------------------
// K4: out = relu(BN2(h2)) -> output dtype
// ---------------------------------------------------------------------------
template<bool BF>
__global__ __launch_bounds__(256) void bn2_out_kernel(
    const float* __restrict__ h2, const float* __restrict__ statsIn,
    const void* __restrict__ g, const void* __restrict__ beta,
    void* __restrict__ out, int M, const int* __restrict__ flag) {
    if ((*flag != 0) != BF) return;
    __shared__ float scaleL[NDIM];
    __shared__ float shiftL[NDIM];
    const int tid = threadIdx.x;
    if (tid < NDIM) {
        float s = statsIn[tid], qv = statsIn[NDIM + tid];
        float invM = 1.0f / (float)M;
        float mean = s * invM;
        float var = fmaxf(qv * invM - mean * mean, 0.0f) + 1e-5f;
        float sc = ld1<BF>(g, tid) * rsqrtf(var);
        scaleL[tid] = sc;
        shiftL[tid] = ld1<BF>(beta, tid) - mean * sc;
    }
    __syncthreads();

    const int n4 = M * NDIM / 4;
    for (int i = blockIdx.x * 256 + tid; i < n4; i += gridDim.x * 256) {
        int c = (i & 31) * 4;
        float4 hv = *(const float4*)(h2 + (long)i * 4);
        float o0 = fmaxf(hv.x * scaleL[c + 0] + shiftL[c + 0], 0.0f);
        float o1 = fmaxf(hv.y * scaleL[c + 1] + shiftL[c + 1], 0.0f);
        float o2 = fmaxf(hv.z * scaleL[c + 2] + shiftL[c + 2], 0.0f);
        float o3 = fmaxf(hv.w * scaleL[c + 3] + shiftL[c + 3], 0.0f);
        if (BF) {
            ushort4 o;
            o.x = f2bf(o0); o.y = f2bf(o1); o.z = f2bf(o2); o.w = f2bf(o3);
            *(ushort4*)((u16*)out + (long)i * 4) = o;
        } else {
            *(float4*)((float*)out + (long)i * 4) = make_float4(o0, o1, o2, o3);
        }
    }
}

extern "C" void kernel_launch(void* const* d_in, const int* in_sizes, int n_in,
                              void* d_out, int out_size, void* d_ws, size_t ws_size,
                              hipStream_t stream) {
    const void* x         = d_in[0];
    const int*  ei        = (const int*)d_in[1];
    const void* edge_attr = d_in[2];
    const void* eps_p     = d_in[3];
    const void* We        = d_in[4];
    const void* be        = d_in[5];
    const void* W1        = d_in[6];
    const void* b1        = d_in[7];
    const void* g1        = d_in[8];
    const void* beta1     = d_in[9];
    const void* W2        = d_in[10];
    const void* b2        = d_in[11];
    const void* g2        = d_in[12];
    const void* beta2     = d_in[13];

    const int N = in_sizes[0] / NDIM;          // 50000
    const int E = in_sizes[1] / 2;             // 800000
    const size_t nd = (size_t)N * NDIM;        // 6.4M

    float* agg    = (float*)d_ws;              // [nd]; reused as h2
    float* h1     = agg + nd;                  // [nd]
    float* stats1 = h1 + nd;                   // [256]
    float* stats2 = stats1 + 256;              // [256]
    int*   flag   = (int*)(stats2 + 256);      // [4]
    float* h2     = agg;                       // reuse

    // CSR scratch overlaid on h1 (dead before gemm1 writes h1)
    int* cnt     = (int*)h1;                   // [N]
    int* cur     = cnt + N;                    // [N]
    int* row_ptr = cur + N;                    // [N+1]
    int* eidx    = row_ptr + N + 1;            // [E]
    int* src_s   = eidx + E;                   // [E]

    detect_kernel<<<1, 64, 0, stream>>>(x, flag);
    hipMemsetAsync(stats1, 0, 512 * sizeof(float), stream);
    hipMemsetAsync(cnt, 0, 2 * (size_t)N * sizeof(int), stream);

    const int eblk = (E + 255) / 256;
    hist_kernel<<<eblk, 256, 0, stream>>>(ei, cnt, E);
    scan_kernel<<<1, 1024, 0, stream>>>(cnt, row_ptr, N);
    scatter_kernel<<<eblk, 256, 0, stream>>>(ei, row_ptr, cur, eidx, src_s, E);

    agg_mfma_kernel<<<2048, 256, 0, stream>>>(row_ptr, eidx, src_s,
        (const u16*)edge_attr, (const u16*)x, (const u16*)We, (const u16*)be,
        agg, N, flag);
    agg_f32_kernel<<<1024, 256, 0, stream>>>(row_ptr, eidx, src_s,
        edge_attr, x, We, be, agg, N, flag);

    const int nblk = (N + 63) / 64;
    gemm1_kernel<false><<<nblk, 256, 0, stream>>>(x, agg, eps_p, W1, b1, h1, stats1, N, flag);
    gemm1_kernel<true ><<<nblk, 256, 0, stream>>>(x, agg, eps_p, W1, b1, h1, stats1, N, flag);

    gemm2_kernel<false><<<nblk, 256, 0, stream>>>(h1, stats1, g1, beta1, W2, b2, h2, stats2, N, flag);
    gemm2_kernel<true ><<<nblk, 256, 0, stream>>>(h1, stats1, g1, beta1, W2, b2, h2, stats2, N, flag);

    bn2_out_kernel<false><<<2048, 256, 0, stream>>>(h2, stats2, g2, beta2, d_out, N, flag);
    bn2_out_kernel<true ><<<2048, 256, 0, stream>>>(h2, stats2, g2, beta2, d_out, N, flag);
}